// Round 3
// baseline (911.012 us; speedup 1.0000x reference)
//
#include <hip/hip_runtime.h>

#define UV_END_ 15360
#define MODOUT_ 16896

typedef __attribute__((ext_vector_type(8))) short s8v;
typedef __attribute__((ext_vector_type(4))) short s4v;
typedef __attribute__((ext_vector_type(8))) __bf16 bf16x8;
typedef __attribute__((ext_vector_type(4))) float f4v;

static __device__ __forceinline__ unsigned short f2bf(float f) {
  unsigned u = __float_as_uint(f);
  u += 0x7fffu + ((u >> 16) & 1u);
  return (unsigned short)(u >> 16);
}
static __device__ __forceinline__ float bf2f(unsigned short s) {
  return __uint_as_float(((unsigned)s) << 16);
}

// ---------------- modulation net ----------------

__global__ void k_ln(const float* __restrict__ latent, const float* __restrict__ g,
                     const float* __restrict__ bb, float* __restrict__ nrm) {
  __shared__ float rs[256], rq[256];
  int b = blockIdx.x, t = threadIdx.x;
  float a0 = latent[b * 512 + t], a1 = latent[b * 512 + t + 256];
  rs[t] = a0 + a1; rq[t] = a0 * a0 + a1 * a1;
  __syncthreads();
  for (int k = 128; k > 0; k >>= 1) {
    if (t < k) { rs[t] += rs[t + k]; rq[t] += rq[t + k]; }
    __syncthreads();
  }
  float mean = rs[0] * (1.0f / 512.0f);
  float var = rq[0] * (1.0f / 512.0f) - mean * mean;
  float rstd = rsqrtf(var + 1e-5f);
  nrm[b * 512 + t]       = (a0 - mean) * rstd * g[t] + bb[t];
  nrm[b * 512 + t + 256] = (a1 - mean) * rstd * g[t + 256] + bb[t + 256];
}

// hout[b][o] = leaky( (res?res[b][o]:0) + bias[o] + sum_i hin[b][i]*W[o][i] )
__global__ void k_modlin(const float* __restrict__ hin, const float* __restrict__ W,
                         const float* __restrict__ bias, const float* __restrict__ res,
                         float* __restrict__ hout) {
  __shared__ float hs[512];
  int b = blockIdx.y, t = threadIdx.x;
  hs[t] = hin[b * 512 + t];
  hs[t + 256] = hin[b * 512 + t + 256];
  __syncthreads();
  int o = blockIdx.x * 256 + t;
  const f4v* wr = (const f4v*)(W + (size_t)o * 512);
  float acc = bias[o];
  #pragma unroll 8
  for (int c = 0; c < 128; ++c) {
    f4v w = wr[c];
    acc += w.x * hs[c * 4] + w.y * hs[c * 4 + 1] + w.z * hs[c * 4 + 2] + w.w * hs[c * 4 + 3];
  }
  if (res) acc += res[b * 512 + o];
  hout[b * 512 + o] = acc > 0.f ? acc : 0.01f * acc;
}

__global__ void k_modout(const float* __restrict__ h, const float* __restrict__ Wm,
                         const float* __restrict__ bm, const float* __restrict__ Wlast,
                         float* __restrict__ modout, float* __restrict__ Wfin) {
  int t = threadIdx.x;
  int o = blockIdx.x * 8 + (t >> 5);
  int b = t & 31;
  const f4v* wr = (const f4v*)(Wm + (size_t)o * 512);
  const f4v* hr = (const f4v*)(h + b * 512);
  float acc = bm[o];
  #pragma unroll 4
  for (int c = 0; c < 128; ++c) {
    f4v w = wr[c], v = hr[c];
    acc += w.x * v.x + w.y * v.y + w.z * v.z + w.w * v.w;
  }
  if (o < UV_END_) {
    modout[(size_t)b * MODOUT_ + o] = acc;
  } else {
    int r = o - UV_END_;
    int od = r >> 9, hh = r & 511;
    float s = 1.f / (1.f + __expf(-acc));
    Wfin[(b * 3 + od) * 512 + hh] = s * Wlast[od * 512 + hh];
  }
}

// Wmod[b][l][h][i] = (sigmoid(sum_r U[b,l,h,r]*V[b,l,i,r]) + 1) * Wh[l][h][i]  (bf16)
__global__ void k_wprep(const float* __restrict__ modout, const float* __restrict__ Wh,
                        unsigned short* __restrict__ Wmod) {
  __shared__ float Vs[2560];
  __shared__ float Us[320];
  int ht = blockIdx.x, l = blockIdx.y, b = blockIdx.z, t = threadIdx.x;
  const float* mo = modout + (size_t)b * MODOUT_ + l * 5120;
  for (int i = t; i < 2560; i += 256) Vs[i] = mo[2560 + i];
  for (int i = t; i < 320; i += 256) Us[i] = mo[ht * 320 + i];
  __syncthreads();
  int hl = t >> 2;
  int h = ht * 64 + hl;
  float u0 = Us[hl * 5], u1 = Us[hl * 5 + 1], u2 = Us[hl * 5 + 2],
        u3 = Us[hl * 5 + 3], u4 = Us[hl * 5 + 4];
  const float* whr = Wh + ((size_t)(l * 512 + h)) * 512;
  unsigned short* wmr = Wmod + (((size_t)(b * 3 + l)) * 512 + h) * 512;
  for (int c = 0; c < 16; ++c) {
    int i0 = (t & 3) * 128 + c * 8;
    s8v pk;
    #pragma unroll
    for (int j = 0; j < 8; ++j) {
      int i = i0 + j;
      float gg = u0 * Vs[i * 5] + u1 * Vs[i * 5 + 1] + u2 * Vs[i * 5 + 2]
               + u3 * Vs[i * 5 + 3] + u4 * Vs[i * 5 + 4];
      float sg = 1.f / (1.f + __expf(-gg));
      float m = (sg + 1.f) * whr[i];
      pk[j] = (short)f2bf(m);
    }
    *(s8v*)(wmr + i0) = pk;
  }
}

// ---------------- fused SIREN main ----------------
// Per block: batch b, 64-row tile. h tile [64][512] bf16 in LDS, XOR-swizzled:
//   slot(n,i) = n*512 + (i ^ ((n&7)<<3))    (XOR on 8-elem/16B granularity)
// GEMM computes transposed product D[hh,n] = sum_i Wmod[hh,i]*h[n,i] so that
// C-fragment rows (contiguous per lane) are hh -> 8-byte contiguous LDS writes.
__global__ __launch_bounds__(256, 2) void k_main(
    const float* __restrict__ x, const float* __restrict__ W0w,
    const float* __restrict__ b0, const unsigned short* __restrict__ Wmod,
    const float* __restrict__ bh, const float* __restrict__ Wfin,
    const float* __restrict__ blast, float* __restrict__ out) {
  __shared__ unsigned short hlds[64 * 512];
  const int b = blockIdx.y, tile = blockIdx.x, t = threadIdx.x;
  const int lane = t & 63, wv = t >> 6;
  const int n0 = tile * 64;

  // ---- layer 0: h = sin(30*(x @ W0^T + b0)) straight into LDS
  {
    int n = t >> 2;
    float x0 = x[((size_t)b * 4096 + n0 + n) * 2 + 0];
    float x1 = x[((size_t)b * 4096 + n0 + n) * 2 + 1];
    int swz = (n & 7) << 3;
    for (int c = 0; c < 16; ++c) {
      int i0 = (t & 3) * 128 + c * 8;
      s8v pk;
      #pragma unroll
      for (int j = 0; j < 8; ++j) {
        int i = i0 + j;
        float pre = x0 * W0w[i * 2] + x1 * W0w[i * 2 + 1] + b0[i];
        pk[j] = (short)f2bf(__sinf(30.0f * pre));
      }
      *(s8v*)&hlds[n * 512 + (i0 ^ swz)] = pk;
    }
  }
  __syncthreads();

  const int arow = lane & 15;        // A row / B col / D col selector
  const int kgrp = (lane >> 4) * 8;  // k-group base within 32-K step
  const int hbase = wv * 128;        // this wave's hh range

  for (int l = 0; l < 3; ++l) {
    const unsigned short* wp = Wmod + (((size_t)b * 3 + l) << 18)
                             + (size_t)(hbase + arow) * 512 + kgrp;
    f4v acc[8][4];
    #pragma unroll
    for (int fi = 0; fi < 8; ++fi)
      #pragma unroll
      for (int fj = 0; fj < 4; ++fj) { f4v z = {0.f, 0.f, 0.f, 0.f}; acc[fi][fj] = z; }

    s8v abuf0[8], abuf1[8];
    #pragma unroll
    for (int fi = 0; fi < 8; ++fi) abuf0[fi] = *(const s8v*)(wp + fi * 16 * 512);

    #pragma unroll 1
    for (int ks = 0; ks < 16; ks += 2) {
      { // even step: compute ks with abuf0, prefetch ks+1 -> abuf1
        #pragma unroll
        for (int fi = 0; fi < 8; ++fi)
          abuf1[fi] = *(const s8v*)(wp + fi * 16 * 512 + (ks + 1) * 32);
        int icol = ks * 32 + kgrp;
        bf16x8 bv[4];
        #pragma unroll
        for (int fj = 0; fj < 4; ++fj) {
          int n = fj * 16 + arow;
          bv[fj] = __builtin_bit_cast(bf16x8,
                     *(const s8v*)&hlds[n * 512 + (icol ^ ((n & 7) << 3))]);
        }
        #pragma unroll
        for (int fi = 0; fi < 8; ++fi) {
          bf16x8 av = __builtin_bit_cast(bf16x8, abuf0[fi]);
          #pragma unroll
          for (int fj = 0; fj < 4; ++fj)
            acc[fi][fj] = __builtin_amdgcn_mfma_f32_16x16x32_bf16(av, bv[fj], acc[fi][fj], 0, 0, 0);
        }
      }
      { // odd step: compute ks+1 with abuf1, prefetch ks+2 -> abuf0
        int ks2 = (ks + 2 < 16) ? (ks + 2) : 14;  // clamp: last prefetch is dead
        #pragma unroll
        for (int fi = 0; fi < 8; ++fi)
          abuf0[fi] = *(const s8v*)(wp + fi * 16 * 512 + ks2 * 32);
        int icol = (ks + 1) * 32 + kgrp;
        bf16x8 bv[4];
        #pragma unroll
        for (int fj = 0; fj < 4; ++fj) {
          int n = fj * 16 + arow;
          bv[fj] = __builtin_bit_cast(bf16x8,
                     *(const s8v*)&hlds[n * 512 + (icol ^ ((n & 7) << 3))]);
        }
        #pragma unroll
        for (int fi = 0; fi < 8; ++fi) {
          bf16x8 av = __builtin_bit_cast(bf16x8, abuf1[fi]);
          #pragma unroll
          for (int fj = 0; fj < 4; ++fj)
            acc[fi][fj] = __builtin_amdgcn_mfma_f32_16x16x32_bf16(av, bv[fj], acc[fi][fj], 0, 0, 0);
        }
      }
    }
    __syncthreads();  // all waves done READING hlds before overwrite

    // epilogue: h_new[n][hh] = sin(30*(D[hh,n] + bh[hh])), in place
    const float* bhp = bh + l * 512;
    #pragma unroll
    for (int fi = 0; fi < 8; ++fi) {
      int hh = hbase + fi * 16 + (lane >> 4) * 4;
      float bv0 = bhp[hh], bv1 = bhp[hh + 1], bv2 = bhp[hh + 2], bv3 = bhp[hh + 3];
      #pragma unroll
      for (int fj = 0; fj < 4; ++fj) {
        int n = fj * 16 + arow;
        f4v a = acc[fi][fj];
        s4v pk;
        pk[0] = (short)f2bf(__sinf(30.f * (a.x + bv0)));
        pk[1] = (short)f2bf(__sinf(30.f * (a.y + bv1)));
        pk[2] = (short)f2bf(__sinf(30.f * (a.z + bv2)));
        pk[3] = (short)f2bf(__sinf(30.f * (a.w + bv3)));
        *(s4v*)&hlds[n * 512 + (hh ^ ((n & 7) << 3))] = pk;
      }
    }
    __syncthreads();
  }

  // ---- final projection: out[n][o] = h[n][:] . Wfin[b][o][:] + blast[o] + 0.5
  if (t < 192) {
    int n = t / 3, o = t - n * 3;
    const f4v* wf = (const f4v*)(Wfin + ((size_t)b * 3 + o) * 512);
    int swz = (n & 7) << 3;
    float acc = 0.f;
    #pragma unroll 4
    for (int c = 0; c < 64; ++c) {
      int i0 = c * 8;
      s8v hv = *(const s8v*)&hlds[n * 512 + (i0 ^ swz)];
      f4v w0 = wf[c * 2], w1 = wf[c * 2 + 1];
      acc += bf2f((unsigned short)hv[0]) * w0.x + bf2f((unsigned short)hv[1]) * w0.y
           + bf2f((unsigned short)hv[2]) * w0.z + bf2f((unsigned short)hv[3]) * w0.w
           + bf2f((unsigned short)hv[4]) * w1.x + bf2f((unsigned short)hv[5]) * w1.y
           + bf2f((unsigned short)hv[6]) * w1.z + bf2f((unsigned short)hv[7]) * w1.w;
    }
    out[((size_t)b * 4096 + n0 + n) * 3 + o] = acc + blast[o] + 0.5f;
  }
}

extern "C" void kernel_launch(void* const* d_in, const int* in_sizes, int n_in,
                              void* d_out, int out_size, void* d_ws, size_t ws_size,
                              hipStream_t stream) {
  const float* x      = (const float*)d_in[0];
  const float* latent = (const float*)d_in[1];
  const float* W0w    = (const float*)d_in[2];
  const float* b0     = (const float*)d_in[3];
  const float* Wh     = (const float*)d_in[4];
  const float* bh     = (const float*)d_in[5];
  const float* Wlast  = (const float*)d_in[6];
  const float* blast  = (const float*)d_in[7];
  const float* ln_g   = (const float*)d_in[8];
  const float* ln_b   = (const float*)d_in[9];
  const float* Wm_in  = (const float*)d_in[10];
  const float* bm_in  = (const float*)d_in[11];
  const float* Wr1    = (const float*)d_in[12];
  const float* br1    = (const float*)d_in[13];
  const float* Wr2    = (const float*)d_in[14];
  const float* br2    = (const float*)d_in[15];
  const float* Wm_out = (const float*)d_in[16];
  const float* bm_out = (const float*)d_in[17];
  float* out = (float*)d_out;

  // workspace layout (all 16B-aligned)
  float* nrm    = (float*)d_ws;                  // 32*512
  float* h1     = nrm + 32 * 512;                // 32*512
  float* h2     = h1 + 32 * 512;                 // 32*512
  float* tb     = h2 + 32 * 512;                 // 32*512
  float* modout = tb + 32 * 512;                 // 32*16896
  float* Wfin   = modout + (size_t)32 * MODOUT_; // 32*3*512
  unsigned short* Wmod = (unsigned short*)(Wfin + 32 * 3 * 512); // 32*3*512*512 bf16 = 48MB

  k_ln<<<32, 256, 0, stream>>>(latent, ln_g, ln_b, nrm);
  k_modlin<<<dim3(2, 32), 256, 0, stream>>>(nrm, Wm_in, bm_in, nullptr, h1);
  k_modlin<<<dim3(2, 32), 256, 0, stream>>>(h1, Wr1, br1, nullptr, tb);
  k_modlin<<<dim3(2, 32), 256, 0, stream>>>(tb, Wr2, br2, h1, h2);
  k_modlin<<<dim3(2, 32), 256, 0, stream>>>(h2, Wr1 + 512 * 512, br1 + 512, nullptr, tb);
  k_modlin<<<dim3(2, 32), 256, 0, stream>>>(tb, Wr2 + 512 * 512, br2 + 512, h2, h1);
  k_modout<<<2112, 256, 0, stream>>>(h1, Wm_out, bm_out, Wlast, modout, Wfin);
  k_wprep<<<dim3(8, 3, 32), 256, 0, stream>>>(modout, Wh, Wmod);
  k_main<<<dim3(64, 32), 256, 0, stream>>>(x, W0w, b0, Wmod, bh, Wfin, blast, out);
}